// Round 2
// baseline (598.067 us; speedup 1.0000x reference)
//
#include <hip/hip_runtime.h>

// Problem constants (B=4, C=256, H=W=64, heads=4)
#define NPOS   4096          // H*W
#define TOTP   16384         // B*NPOS
#define C      256
#define DH     64

typedef unsigned short ushort_t;
typedef __attribute__((ext_vector_type(8))) short short8;   // 8 bf16 (4 VGPRs) MFMA A/B frag
typedef __attribute__((ext_vector_type(4))) float f32x4;    // MFMA C/D frag

__device__ __forceinline__ f32x4 mfma16(short8 a, short8 b, f32x4 c) {
  return __builtin_amdgcn_mfma_f32_16x16x32_bf16(a, b, c, 0, 0, 0);
}

// fp32 -> bf16 bits, round-to-nearest-even (inputs finite)
__device__ __forceinline__ ushort_t f2bf(float f) {
  union { float f; unsigned int u; } v;
  v.f = f;
  unsigned int r = v.u + 0x7FFFu + ((v.u >> 16) & 1u);
  return (ushort_t)(r >> 16);
}
__device__ __forceinline__ float bf2f(ushort_t u) {
  union { unsigned int u; float f; } v;
  v.u = ((unsigned int)u) << 16;
  return v.f;
}

// ---------------------------------------------------------------------------
// Pack weights to bf16. Q rows (o<256) of w_qkv get the 1/8 attention scale
// folded in (exact in bf16: exponent shift).
__global__ __launch_bounds__(256) void pack_w(const float* __restrict__ wq,
                                              const float* __restrict__ wp,
                                              ushort_t* __restrict__ wqb,
                                              ushort_t* __restrict__ wpb) {
  int idx = blockIdx.x * 256 + threadIdx.x;
  if (idx < 49152) {                       // w_qkv: 768*256 = 196608 = 49152*4
    float4 v = *(const float4*)(wq + (size_t)idx * 4);
    float sc = (idx * 4 < 65536) ? 0.125f : 1.0f;   // rows [0,256) = Q channels
    ushort_t* d = wqb + (size_t)idx * 4;
    unsigned long long pk =
        (unsigned long long)f2bf(v.x * sc) |
        ((unsigned long long)f2bf(v.y * sc) << 16) |
        ((unsigned long long)f2bf(v.z * sc) << 32) |
        ((unsigned long long)f2bf(v.w * sc) << 48);
    *(unsigned long long*)d = pk;
  } else {                                 // w_proj: 256*256 = 65536 = 16384*4
    int j = idx - 49152;
    float4 v = *(const float4*)(wp + (size_t)j * 4);
    ushort_t* d = wpb + (size_t)j * 4;
    unsigned long long pk =
        (unsigned long long)f2bf(v.x) |
        ((unsigned long long)f2bf(v.y) << 16) |
        ((unsigned long long)f2bf(v.z) << 32) |
        ((unsigned long long)f2bf(v.w) << 48);
    *(unsigned long long*)d = pk;
  }
}

// ---------------------------------------------------------------------------
// x [b][c][n] fp32  ->  xT [b*4096+n][c] bf16   (LDS tile transpose)
__global__ __launch_bounds__(256) void transpose_pack(const float* __restrict__ x,
                                                      ushort_t* __restrict__ xT) {
  __shared__ ushort_t tile[64][68];
  int nb = blockIdx.x * 64, cb = blockIdx.y * 64, b = blockIdx.z;
  int tr = threadIdx.x >> 4;            // 0..15
  int tc = (threadIdx.x & 15) * 4;      // 0..60
  const float* src = x + ((size_t)b * C + cb) * NPOS + nb;
#pragma unroll
  for (int it = 0; it < 4; ++it) {
    int c = tr + it * 16;
    float4 v = *(const float4*)(src + (size_t)c * NPOS + tc);
    tile[c][tc + 0] = f2bf(v.x);
    tile[c][tc + 1] = f2bf(v.y);
    tile[c][tc + 2] = f2bf(v.z);
    tile[c][tc + 3] = f2bf(v.w);
  }
  __syncthreads();
  ushort_t* dst = xT + ((size_t)b * NPOS + nb) * C + cb;
#pragma unroll
  for (int it = 0; it < 4; ++it) {
    int n = tr + it * 16;
    unsigned long long pk =
        (unsigned long long)tile[tc + 0][n] |
        ((unsigned long long)tile[tc + 1][n] << 16) |
        ((unsigned long long)tile[tc + 2][n] << 32) |
        ((unsigned long long)tile[tc + 3][n] << 48);
    *(unsigned long long*)(dst + (size_t)n * C + tc) = pk;
  }
}

// ---------------------------------------------------------------------------
// QK GEMM: qk[p][o] = sum_c xT[p][c] * Wq[o][c],  o in [0,512)  (Q pre-scaled)
// wave = 32 p x 64 o. grid (128 p-tiles, 8 o-tiles).
__global__ __launch_bounds__(256) void gemm_qk(const ushort_t* __restrict__ xT,
                                               const ushort_t* __restrict__ Wq,
                                               ushort_t* __restrict__ qk) {
  int w = threadIdx.x >> 6, l = threadIdx.x & 63;
  int lr = l & 15, lg = l >> 4;
  int mbase = blockIdx.x * 128 + w * 32;
  int nbase = blockIdx.y * 64;
  f32x4 acc[2][4] = {};
#pragma unroll
  for (int kk = 0; kk < 8; ++kk) {
    short8 a0 = *(const short8*)(xT + (size_t)(mbase + lr) * C + kk * 32 + lg * 8);
    short8 a1 = *(const short8*)(xT + (size_t)(mbase + 16 + lr) * C + kk * 32 + lg * 8);
#pragma unroll
    for (int t = 0; t < 4; ++t) {
      short8 b = *(const short8*)(Wq + (size_t)(nbase + t * 16 + lr) * C + kk * 32 + lg * 8);
      acc[0][t] = mfma16(a0, b, acc[0][t]);
      acc[1][t] = mfma16(a1, b, acc[1][t]);
    }
  }
#pragma unroll
  for (int qq = 0; qq < 2; ++qq)
#pragma unroll
    for (int t = 0; t < 4; ++t)
#pragma unroll
      for (int i = 0; i < 4; ++i)
        qk[(size_t)(mbase + qq * 16 + lg * 4 + i) * 512 + nbase + t * 16 + lr] =
            f2bf(acc[qq][t][i]);
}

// ---------------------------------------------------------------------------
// V GEMM with swapped roles: vT[b*256 + ov][n] = sum_c Wq[512+ov][c]*xT[p][c]
// Output is V already transposed (d-major). wave = 32 ov x 64 p.
// grid (256 p-tiles, 2 ov-tiles).
__global__ __launch_bounds__(256) void gemm_v(const ushort_t* __restrict__ xT,
                                              const ushort_t* __restrict__ Wq,
                                              ushort_t* __restrict__ vT) {
  int w = threadIdx.x >> 6, l = threadIdx.x & 63;
  int lr = l & 15, lg = l >> 4;
  int obase = blockIdx.y * 128 + w * 32;       // 0..255 (V channel)
  int pbase = blockIdx.x * 64;
  f32x4 acc[2][4] = {};
#pragma unroll
  for (int kk = 0; kk < 8; ++kk) {
    short8 a0 = *(const short8*)(Wq + (size_t)(512 + obase + lr) * C + kk * 32 + lg * 8);
    short8 a1 = *(const short8*)(Wq + (size_t)(512 + obase + 16 + lr) * C + kk * 32 + lg * 8);
#pragma unroll
    for (int t = 0; t < 4; ++t) {
      short8 b = *(const short8*)(xT + (size_t)(pbase + t * 16 + lr) * C + kk * 32 + lg * 8);
      acc[0][t] = mfma16(a0, b, acc[0][t]);
      acc[1][t] = mfma16(a1, b, acc[1][t]);
    }
  }
#pragma unroll
  for (int qq = 0; qq < 2; ++qq)
#pragma unroll
    for (int i = 0; i < 4; ++i) {
      int ov = obase + qq * 16 + lg * 4 + i;
#pragma unroll
      for (int t = 0; t < 4; ++t) {
        int p = pbase + t * 16 + lr;
        vT[((size_t)((p >> 12) * 256 + ov)) * NPOS + (p & 4095)] = f2bf(acc[qq][i? t:t][i]);
      }
    }
}

// ---------------------------------------------------------------------------
// Flash attention, no-barrier main loop, split-K across wave pairs.
// Block = 4 waves = 2 pairs; each pair owns 32 q-rows; wave (pair, half) does
// kt = half*32 .. half*32+31. K frags direct from qk[p][512] (d-contig, 128B
// aligned rows); V^T frags direct from vT (key-contig). P bounced through
// per-wave XOR-swizzled LDS. One barrier total (before the m/l/O merge).
__global__ __launch_bounds__(256, 4) void attn_kernel(const ushort_t* __restrict__ qk,
                                                      const ushort_t* __restrict__ vT,
                                                      ushort_t* __restrict__ ao) {
  __shared__ ushort_t Pw[4][2048];        // per-wave P [32 q][64 key], swizzled
  __shared__ ushort_t Ob[4][32][64];      // unnormalized O (bf16) for merge
  __shared__ float    Mb[4][32], Lb[4][32];

  int w = threadIdx.x >> 6, l = threadIdx.x & 63;
  int lr = l & 15, lg = l >> 4;
  int pairid = w >> 1, half = w & 1;

  // XCD-aware remap: 2 bh per XCD -> K/V working set (~2MB) L2-resident.
  int lin = blockIdx.y * gridDim.x + blockIdx.x;   // 0..1023
  int xcd = lin & 7, slot = lin >> 3;              // slot 0..127
  int bh = xcd * 2 + (slot >> 6);
  int qtile = slot & 63;                           // 0..63
  int b = bh >> 2, h = bh & 3;
  size_t bbase = (size_t)b * NPOS;
  int qbase0 = qtile * 64;
  int qbase = qbase0 + pairid * 32;                // this pair's 32 q-rows

  const ushort_t* qkb = qk + bbase * 512;
  const ushort_t* vTb = vT + ((size_t)(b * 256 + h * DH)) * NPOS;

  // Q fragments hoisted (scale pre-folded into W_q)
  short8 aq[2][2];
#pragma unroll
  for (int qq = 0; qq < 2; ++qq)
#pragma unroll
    for (int ks = 0; ks < 2; ++ks)
      aq[qq][ks] = *(const short8*)(qkb + (size_t)(qbase + qq * 16 + lr) * 512 +
                                    h * DH + ks * 32 + lg * 8);

  f32x4 o[2][4] = {};
  float mi[2][4] = {{-1e30f, -1e30f, -1e30f, -1e30f}, {-1e30f, -1e30f, -1e30f, -1e30f}};
  float li[2][4] = {};

  for (int kt = half * 32; kt < half * 32 + 32; ++kt) {
    const ushort_t* kbase = qkb + (size_t)(kt * 64) * 512 + 256 + h * DH;
    // ---- S = Q K^T ----
    f32x4 s[2][4] = {};
#pragma unroll
    for (int ks = 0; ks < 2; ++ks) {
      short8 bk[4];
#pragma unroll
      for (int t = 0; t < 4; ++t)
        bk[t] = *(const short8*)(kbase + (size_t)(t * 16 + lr) * 512 + ks * 32 + lg * 8);
#pragma unroll
      for (int qq = 0; qq < 2; ++qq)
#pragma unroll
        for (int t = 0; t < 4; ++t)
          s[qq][t] = mfma16(aq[qq][ks], bk[t], s[qq][t]);
    }

    // issue first half of V frags early (latency hides under softmax)
    short8 bv0[4];
#pragma unroll
    for (int t = 0; t < 4; ++t)
      bv0[t] = *(const short8*)(vTb + (size_t)(t * 16 + lr) * NPOS + kt * 64 + lg * 8);

    // ---- online softmax; rows q = qq*16 + lg*4 + i; 16 lr-lanes hold the keys
    #pragma unroll
    for (int qq = 0; qq < 2; ++qq) {
#pragma unroll
      for (int i = 0; i < 4; ++i) {
        float mx = fmaxf(fmaxf(s[qq][0][i], s[qq][1][i]), fmaxf(s[qq][2][i], s[qq][3][i]));
#pragma unroll
        for (int msk = 1; msk <= 8; msk <<= 1) mx = fmaxf(mx, __shfl_xor(mx, msk, 64));
        float mnew = fmaxf(mi[qq][i], mx);
        float corr = __expf(mi[qq][i] - mnew);
        int r = qq * 16 + lg * 4 + i;
        float rs = 0.f;
#pragma unroll
        for (int t = 0; t < 4; ++t) {
          float p = __expf(s[qq][t][i] - mnew);
          rs += p;
          Pw[w][r * 64 + ((t * 16 + lr) ^ ((r & 7) << 3))] = f2bf(p);
        }
#pragma unroll
        for (int msk = 1; msk <= 8; msk <<= 1) rs += __shfl_xor(rs, msk, 64);
        li[qq][i] = li[qq][i] * corr + rs;
        mi[qq][i] = mnew;
#pragma unroll
        for (int t = 0; t < 4; ++t) o[qq][t][i] *= corr;
      }
    }

    // ---- O += P V ----  (second half of V frags loads under kk=0 MFMAs)
    short8 bv1[4];
#pragma unroll
    for (int t = 0; t < 4; ++t)
      bv1[t] = *(const short8*)(vTb + (size_t)(t * 16 + lr) * NPOS + kt * 64 + 32 + lg * 8);
#pragma unroll
    for (int qq = 0; qq < 2; ++qq) {
      int r = qq * 16 + lr;
      short8 ap0 = *(const short8*)&Pw[w][r * 64 + ((lg * 8) ^ ((r & 7) << 3))];
#pragma unroll
      for (int t = 0; t < 4; ++t) o[qq][t] = mfma16(ap0, bv0[t], o[qq][t]);
      short8 ap1 = *(const short8*)&Pw[w][r * 64 + ((32 + lg * 8) ^ ((r & 7) << 3))];
#pragma unroll
      for (int t = 0; t < 4; ++t) o[qq][t] = mfma16(ap1, bv1[t], o[qq][t]);
    }
  }

  // ---- stash partial (m, l, O) and merge the two kt-halves of each pair ----
#pragma unroll
  for (int qq = 0; qq < 2; ++qq)
#pragma unroll
    for (int i = 0; i < 4; ++i) {
      int r = qq * 16 + lg * 4 + i;
      if (lr == 0) { Mb[w][r] = mi[qq][i]; Lb[w][r] = li[qq][i]; }
#pragma unroll
      for (int t = 0; t < 4; ++t) Ob[w][r][t * 16 + lr] = f2bf(o[qq][t][i]);
    }
  __syncthreads();

  {
    int wA = pairid * 2, wB = wA + 1, qsel = half;   // wave handles its qq-half
#pragma unroll
    for (int i = 0; i < 4; ++i) {
      int r = qsel * 16 + lg * 4 + i;
      float mA = Mb[wA][r], mB = Mb[wB][r];
      float m = fmaxf(mA, mB);
      float fA = __expf(mA - m), fB = __expf(mB - m);
      float lsum = Lb[wA][r] * fA + Lb[wB][r] * fB;
      float inv = 1.0f / lsum;
      size_t p = bbase + qbase0 + pairid * 32 + r;
#pragma unroll
      for (int t = 0; t < 4; ++t) {
        int c = t * 16 + lr;
        float ov = bf2f(Ob[wA][r][c]) * fA + bf2f(Ob[wB][r][c]) * fB;
        ao[p * C + h * DH + c] = f2bf(ov * inv);
      }
    }
  }
}

// ---------------------------------------------------------------------------
// Proj GEMM: out[b][o][n] = sum_c Wp[o][c]*ao[p][c] + bias[o]
// wave = 32 o x 64 p. grid (256 p-tiles, 2 o-tiles). fp32 stores to [o][n].
__global__ __launch_bounds__(256) void gemm_proj(const ushort_t* __restrict__ ao,
                                                 const ushort_t* __restrict__ Wp,
                                                 const float* __restrict__ bias,
                                                 float* __restrict__ out) {
  int w = threadIdx.x >> 6, l = threadIdx.x & 63;
  int lr = l & 15, lg = l >> 4;
  int obase = blockIdx.y * 128 + w * 32;
  int pbase = blockIdx.x * 64;
  f32x4 acc[2][4] = {};
#pragma unroll
  for (int kk = 0; kk < 8; ++kk) {
    short8 a0 = *(const short8*)(Wp + (size_t)(obase + lr) * C + kk * 32 + lg * 8);
    short8 a1 = *(const short8*)(Wp + (size_t)(obase + 16 + lr) * C + kk * 32 + lg * 8);
#pragma unroll
    for (int t = 0; t < 4; ++t) {
      short8 b = *(const short8*)(ao + (size_t)(pbase + t * 16 + lr) * C + kk * 32 + lg * 8);
      acc[0][t] = mfma16(a0, b, acc[0][t]);
      acc[1][t] = mfma16(a1, b, acc[1][t]);
    }
  }
#pragma unroll
  for (int qq = 0; qq < 2; ++qq)
#pragma unroll
    for (int i = 0; i < 4; ++i) {
      int oc = obase + qq * 16 + lg * 4 + i;
      float bv = bias[oc];
#pragma unroll
      for (int t = 0; t < 4; ++t) {
        int p = pbase + t * 16 + lr;
        out[((size_t)(p >> 12) * C + oc) * NPOS + (p & 4095)] = acc[qq][t][i] + bv;
      }
    }
}

// ---------------------------------------------------------------------------
extern "C" void kernel_launch(void* const* d_in, const int* in_sizes, int n_in,
                              void* d_out, int out_size, void* d_ws, size_t ws_size,
                              hipStream_t stream) {
  const float* x      = (const float*)d_in[0];
  const float* w_qkv  = (const float*)d_in[1];
  const float* w_proj = (const float*)d_in[2];
  const float* b_proj = (const float*)d_in[3];
  float* out = (float*)d_out;

  char* ws = (char*)d_ws;
  ushort_t* xT  = (ushort_t*)(ws);                 // 16384*256*2  =  8,388,608
  ushort_t* wqb = (ushort_t*)(ws + 8388608);       // 768*256*2    =    393,216
  ushort_t* wpb = (ushort_t*)(ws + 8781824);       // 256*256*2    =    131,072
  ushort_t* qk  = (ushort_t*)(ws + 8912896);       // 16384*512*2  = 16,777,216
  ushort_t* vT  = (ushort_t*)(ws + 25690112);      // 4*256*4096*2 =  8,388,608
  ushort_t* ao  = (ushort_t*)(ws + 34078720);      // 16384*256*2  =  8,388,608
                                                   // total 42,467,328 bytes

  pack_w<<<256, 256, 0, stream>>>(w_qkv, w_proj, wqb, wpb);
  transpose_pack<<<dim3(64, 4, 4), 256, 0, stream>>>(x, xT);
  gemm_qk<<<dim3(128, 8), 256, 0, stream>>>(xT, wqb, qk);
  gemm_v<<<dim3(256, 2), 256, 0, stream>>>(xT, wqb, vT);
  attn_kernel<<<dim3(64, 16), 256, 0, stream>>>(qk, vT, ao);
  gemm_proj<<<dim3(256, 2), 256, 0, stream>>>(ao, wpb, b_proj, out);
}